// Round 8
// baseline (546.366 us; speedup 1.0000x reference)
//
#include <hip/hip_runtime.h>
#include <math.h>

#define D 128
#define D3 384

typedef __attribute__((ext_vector_type(8))) short bf16x8;
typedef __attribute__((ext_vector_type(4))) float f32x4;
typedef __attribute__((ext_vector_type(4))) unsigned int u32x4;

// fast transcendentals (native v_exp_f32 / v_rcp_f32 / v_cos_f32)
__device__ __forceinline__ float fsigmoid(float x){
  return __builtin_amdgcn_rcpf(1.0f + __expf(-x));
}
__device__ __forceinline__ float ftanh(float x){
  float e = __expf(2.0f * x);
  return 1.0f - 2.0f * __builtin_amdgcn_rcpf(e + 1.0f);
}

// round-to-nearest-even f32 -> bf16
__device__ __forceinline__ unsigned short f2bf(float f){
  unsigned u = __float_as_uint(f);
  return (unsigned short)((u + 0x7FFFu + ((u >> 16) & 1u)) >> 16);
}

// LDS slot swizzle: lg-disjoint (even/odd) slot sets -> <=2-way at quarter & half wave
__device__ __forceinline__ int slot16(int c, int row){ return (c + 2 * (row & 7)) & 15; }
__device__ __forceinline__ int slot32(int c, int row){ return (c + 2 * (row & 7)) & 31; }

// ---------- zero small scratch ----------
__global__ __launch_bounds__(256) void k_init0(int* __restrict__ cnt, float* __restrict__ bns,
                                               int* __restrict__ gbh, int n){
  int idx = blockIdx.x * 256 + threadIdx.x;
  if (idx < n) cnt[idx] = 0;
  if (idx < 2 * D) bns[idx] = 0.0f;
  if (idx < 256) gbh[idx] = 0;
}

// ---------- pack ALL weights into per-wave fragment order (coalesced 1KB loads) ----------
__global__ __launch_bounds__(256) void k_wpackall(
    const float* __restrict__ mergeW, const float* __restrict__ g0, const float* __restrict__ g1,
    const float* __restrict__ sk, const float* __restrict__ ih0, const float* __restrict__ hh0,
    const float* __restrict__ ih1, const float* __restrict__ hh1,
    unsigned short* __restrict__ Pm, unsigned short* __restrict__ Pg0, unsigned short* __restrict__ Pg1,
    unsigned short* __restrict__ Psk, unsigned short* __restrict__ Pu0, unsigned short* __restrict__ Pu1){
  int idx = blockIdx.x * 256 + threadIdx.x;
  if (idx < 32768){
    int i = idx;
    int j = i & 7, l15 = (i >> 3) & 15, lg = (i >> 7) & 3, nf = (i >> 9) & 1, kk = (i >> 10) & 7, w = (i >> 13) & 3;
    int col = w * 32 + nf * 16 + l15, k = (kk * 4 + lg) * 8 + j;
    Pm[i] = f2bf(mergeW[k * 128 + col]);
  } else if (idx < 81920){
    int seg = (idx - 32768) >> 14;
    int i = (idx - 32768) & 16383;
    const float* W = seg == 0 ? g0 : (seg == 1 ? g1 : sk);
    unsigned short* P = seg == 0 ? Pg0 : (seg == 1 ? Pg1 : Psk);
    int j = i & 7, l15 = (i >> 3) & 15, lg = (i >> 7) & 3, nf = (i >> 9) & 1, kk = (i >> 10) & 3, w = (i >> 12) & 3;
    int col = w * 32 + nf * 16 + l15, k = (kk * 4 + lg) * 8 + j;
    P[i] = f2bf(W[k * 128 + col]);
  } else if (idx < 278528){
    int seg = (idx - 81920) / 98304;
    int i = (idx - 81920) % 98304;
    const float* Wih = seg ? ih1 : ih0;
    const float* Whh = seg ? hh1 : hh0;
    unsigned short* P = seg ? Pu1 : Pu0;
    int j = i & 7, l15 = (i >> 3) & 15, lg = (i >> 7) & 3;
    int r9 = i >> 9; int t = r9 % 6; int r = r9 / 6; int kk = r & 3, w = r >> 2;
    int col = (t >> 1) * 128 + w * 16 + l15, k = (kk * 4 + lg) * 8 + j;
    P[i] = f2bf((t & 1 ? Whh : Wih)[k * 384 + col]);
  }
}

// ---------- merge GEMM: xb = bf16([nf, cos(ts*freq+phase)] @ mergeW + mergeb) ----------
__global__ __launch_bounds__(256) void k_merge(const float* __restrict__ nf, const float* __restrict__ ts,
                                               const float* __restrict__ freq, const float* __restrict__ phase,
                                               const unsigned short* __restrict__ Pm,  // packed
                                               const float* __restrict__ bias,
                                               unsigned short* __restrict__ xb, int M){
  __shared__ __align__(16) unsigned short Alds[64 * 256];   // 32 KB
  const int tid = threadIdx.x;
  const int lane = tid & 63;
  const int w = tid >> 6;
  const int row0 = blockIdx.y * 64;

  #pragma unroll
  for (int r = 0; r < 8; ++r){
    int u = r * 256 + tid;
    int row = u >> 5, c16 = u & 31;
    int gr = row0 + row;
    union { unsigned short s[8]; bf16x8 v; } t;
    if (gr < M){
      if (c16 < 16){
        const float* p = nf + (size_t)gr * 128 + c16 * 8;
        float4 f0 = *(const float4*)p, f1 = *(const float4*)(p + 4);
        t.s[0]=f2bf(f0.x); t.s[1]=f2bf(f0.y); t.s[2]=f2bf(f0.z); t.s[3]=f2bf(f0.w);
        t.s[4]=f2bf(f1.x); t.s[5]=f2bf(f1.y); t.s[6]=f2bf(f1.z); t.s[7]=f2bf(f1.w);
      } else {
        float tv = ts[gr];
        int ch0 = (c16 - 16) * 8;
        float4 fq0 = *(const float4*)&freq[ch0],  fq1 = *(const float4*)&freq[ch0 + 4];
        float4 ph0 = *(const float4*)&phase[ch0], ph1 = *(const float4*)&phase[ch0 + 4];
        t.s[0]=f2bf(__cosf(tv*fq0.x+ph0.x)); t.s[1]=f2bf(__cosf(tv*fq0.y+ph0.y));
        t.s[2]=f2bf(__cosf(tv*fq0.z+ph0.z)); t.s[3]=f2bf(__cosf(tv*fq0.w+ph0.w));
        t.s[4]=f2bf(__cosf(tv*fq1.x+ph1.x)); t.s[5]=f2bf(__cosf(tv*fq1.y+ph1.y));
        t.s[6]=f2bf(__cosf(tv*fq1.z+ph1.z)); t.s[7]=f2bf(__cosf(tv*fq1.w+ph1.w));
      }
    } else {
      #pragma unroll
      for (int q = 0; q < 8; ++q) t.s[q] = 0;
    }
    *(bf16x8*)&Alds[row * 256 + slot32(c16, row) * 8] = t.v;
  }
  __syncthreads();

  f32x4 acc[4][2];
  #pragma unroll
  for (int mf = 0; mf < 4; ++mf)
    #pragma unroll
    for (int nfi = 0; nfi < 2; ++nfi)
      #pragma unroll
      for (int i = 0; i < 4; ++i) acc[mf][nfi][i] = 0.0f;

  const int l15 = lane & 15, lg = lane >> 4;
  #pragma unroll
  for (int kk = 0; kk < 8; ++kk){
    const int c16 = kk * 4 + lg;
    bf16x8 a[4], b[2];
    #pragma unroll
    for (int nfi = 0; nfi < 2; ++nfi)
      b[nfi] = *(const bf16x8*)&Pm[(size_t)((w * 8 + kk) * 2 + nfi) * 512 + lane * 8];
    #pragma unroll
    for (int mf = 0; mf < 4; ++mf){
      int row = mf * 16 + l15;
      a[mf] = *(bf16x8*)&Alds[row * 256 + slot32(c16, row) * 8];
    }
    #pragma unroll
    for (int mf = 0; mf < 4; ++mf)
      #pragma unroll
      for (int nfi = 0; nfi < 2; ++nfi)
        acc[mf][nfi] = __builtin_amdgcn_mfma_f32_16x16x32_bf16(a[mf], b[nfi], acc[mf][nfi], 0, 0, 0);
  }

  #pragma unroll
  for (int nfi = 0; nfi < 2; ++nfi){
    int c = w * 32 + nfi * 16 + l15;
    float bv = bias[c];
    #pragma unroll
    for (int mf = 0; mf < 4; ++mf)
      #pragma unroll
      for (int i = 0; i < 4; ++i){
        int rr = row0 + mf * 16 + lg * 4 + i;
        if (rr < M) xb[(size_t)rr * 128 + c] = f2bf(acc[mf][nfi][i] + bv);
      }
  }
}

// ---------- bf16 MFMA GEMM (Nc=128) with optional fused attn-coeffs / BN-reduce ----------
template<bool ABF16, bool OUTBF, bool ACCUM, bool BIAS, bool ATTN, bool BNRED>
__global__ __launch_bounds__(256) void k_mgemm(const void* __restrict__ Av,
                                               const unsigned short* __restrict__ Pg,  // packed
                                               const float* __restrict__ bias,
                                               void* __restrict__ Cv, int M,
                                               const float* __restrict__ a_s, const float* __restrict__ a_d,
                                               float* __restrict__ asrc, float* __restrict__ adst,
                                               float* __restrict__ bns){
  __shared__ __align__(16) unsigned short Alds[64 * 128];   // 16 KB
  __shared__ float attS[64], attD[64];                      // ATTN row partials
  __shared__ float bn2[256];                                // BNRED col partials
  const int tid = threadIdx.x;
  const int lane = tid & 63;
  const int w = tid >> 6;
  const int row0 = blockIdx.y * 64;

  if (ATTN){
    if (tid < 64) attS[tid] = 0.0f;
    else if (tid < 128) attD[tid - 64] = 0.0f;
  }
  if (BNRED) bn2[tid] = 0.0f;

  #pragma unroll
  for (int r = 0; r < 4; ++r){
    int u = r * 256 + tid;
    int row = u >> 4, c16 = u & 15;
    int gr = row0 + row;
    int c16s = slot16(c16, row);
    if (ABF16){
      u32x4 v = {0,0,0,0};
      if (gr < M) v = *(const u32x4*)((const unsigned short*)Av + (size_t)gr * 128 + c16 * 8);
      *(u32x4*)&Alds[row * 128 + c16s * 8] = v;
    } else {
      float4 f0 = make_float4(0.f,0.f,0.f,0.f), f1 = f0;
      if (gr < M){
        const float* p = (const float*)Av + (size_t)gr * 128 + c16 * 8;
        f0 = *(const float4*)p; f1 = *(const float4*)(p + 4);
      }
      union { unsigned short s[8]; bf16x8 v; } t;
      t.s[0]=f2bf(f0.x); t.s[1]=f2bf(f0.y); t.s[2]=f2bf(f0.z); t.s[3]=f2bf(f0.w);
      t.s[4]=f2bf(f1.x); t.s[5]=f2bf(f1.y); t.s[6]=f2bf(f1.z); t.s[7]=f2bf(f1.w);
      *(bf16x8*)&Alds[row * 128 + c16s * 8] = t.v;
    }
  }
  __syncthreads();

  f32x4 acc[4][2];
  #pragma unroll
  for (int mf = 0; mf < 4; ++mf)
    #pragma unroll
    for (int nfi = 0; nfi < 2; ++nfi)
      #pragma unroll
      for (int i = 0; i < 4; ++i) acc[mf][nfi][i] = 0.0f;

  const int l15 = lane & 15, lg = lane >> 4;
  #pragma unroll
  for (int kk = 0; kk < 4; ++kk){
    const int c16 = kk * 4 + lg;
    bf16x8 a[4], b[2];
    #pragma unroll
    for (int nfi = 0; nfi < 2; ++nfi)
      b[nfi] = *(const bf16x8*)&Pg[(size_t)((w * 4 + kk) * 2 + nfi) * 512 + lane * 8];
    #pragma unroll
    for (int mf = 0; mf < 4; ++mf){
      int row = mf * 16 + l15;
      a[mf] = *(bf16x8*)&Alds[row * 128 + slot16(c16, row) * 8];
    }
    #pragma unroll
    for (int mf = 0; mf < 4; ++mf)
      #pragma unroll
      for (int nfi = 0; nfi < 2; ++nfi)
        acc[mf][nfi] = __builtin_amdgcn_mfma_f32_16x16x32_bf16(a[mf], b[nfi], acc[mf][nfi], 0, 0, 0);
  }

  const int c0 = w * 32 + l15;       // nfi=0 col
  const int c1 = c0 + 16;            // nfi=1 col
  float as0, as1, ad0, ad1;
  if (ATTN){
    as0 = a_s[c0]; as1 = a_s[c1];
    ad0 = a_d[c0]; ad1 = a_d[c1];
  }

  #pragma unroll
  for (int nfi = 0; nfi < 2; ++nfi){
    int c = w * 32 + nfi * 16 + l15;
    float bv = BIAS ? bias[c] : 0.0f;
    float bs = 0.0f, bq = 0.0f;
    #pragma unroll
    for (int mf = 0; mf < 4; ++mf)
      #pragma unroll
      for (int i = 0; i < 4; ++i){
        int rr = row0 + mf * 16 + lg * 4 + i;
        if (rr < M){
          size_t o = (size_t)rr * 128 + c;
          float v = acc[mf][nfi][i] + bv;
          if (OUTBF){
            ((unsigned short*)Cv)[o] = f2bf(v);
          } else {
            float* C = (float*)Cv;
            if (ACCUM) v += C[o];
            C[o] = v;
          }
          if (BNRED){ bs += v; bq += v * v; }
        }
      }
    if (BNRED){
      atomicAdd(&bn2[c], bs);
      atomicAdd(&bn2[128 + c], bq);
    }
  }

  if (ATTN){
    #pragma unroll
    for (int mf = 0; mf < 4; ++mf)
      #pragma unroll
      for (int i = 0; i < 4; ++i){
        int row = mf * 16 + lg * 4 + i;
        atomicAdd(&attS[row], acc[mf][0][i] * as0 + acc[mf][1][i] * as1);
        atomicAdd(&attD[row], acc[mf][0][i] * ad0 + acc[mf][1][i] * ad1);
      }
    __syncthreads();
    if (tid < 64 && row0 + tid < M){
      asrc[row0 + tid] = attS[tid];
      adst[row0 + tid] = attD[tid];
    }
  }
  if (BNRED){
    __syncthreads();
    atomicAdd(&bns[tid], bn2[tid]);
  }
}

// ---------- CSR build: histogram of dst + coarse bucket histogram ----------
__global__ __launch_bounds__(256) void k_hist(const int* __restrict__ ei, int* __restrict__ cnt,
                                              int* __restrict__ gbh, int e, int etot){
  __shared__ int bh[256];
  bh[threadIdx.x] = 0;
  __syncthreads();
  int i0 = blockIdx.x * 4096;
  int iend = min(i0 + 4096, etot);
  for (int t = i0 + threadIdx.x; t < iend; t += 256){
    int d_ = (t < e) ? ei[e + t] : (t - e);
    atomicAdd(&cnt[d_], 1);
    atomicAdd(&bh[d_ >> 8], 1);
  }
  __syncthreads();
  if (bh[threadIdx.x]) atomicAdd(&gbh[threadIdx.x], bh[threadIdx.x]);
}

__global__ __launch_bounds__(256) void k_scan1(const int* __restrict__ cnt, int* __restrict__ off,
                                               int* __restrict__ bsum, int n){
  __shared__ int sm[256];
  int i = blockIdx.x * 256 + threadIdx.x;
  int v = (i < n) ? cnt[i] : 0;
  sm[threadIdx.x] = v;
  __syncthreads();
  #pragma unroll
  for (int d = 1; d < 256; d <<= 1){
    int t = (threadIdx.x >= d) ? sm[threadIdx.x - d] : 0;
    __syncthreads();
    sm[threadIdx.x] += t;
    __syncthreads();
  }
  if (i < n) off[i] = sm[threadIdx.x] - v;
  if (threadIdx.x == 255) bsum[blockIdx.x] = sm[255];
}

// scan block sums AND bucket histogram -> bucket cursor
__global__ __launch_bounds__(256) void k_scan2(int* __restrict__ bsum, int nb,
                                               const int* __restrict__ gbh, int* __restrict__ gbc){
  __shared__ int sm[256];
  int v = (threadIdx.x < nb) ? bsum[threadIdx.x] : 0;
  sm[threadIdx.x] = v;
  __syncthreads();
  #pragma unroll
  for (int d = 1; d < 256; d <<= 1){
    int t = (threadIdx.x >= d) ? sm[threadIdx.x - d] : 0;
    __syncthreads();
    sm[threadIdx.x] += t;
    __syncthreads();
  }
  if (threadIdx.x < nb) bsum[threadIdx.x] = sm[threadIdx.x] - v;
  __syncthreads();
  int v2 = gbh[threadIdx.x];
  sm[threadIdx.x] = v2;
  __syncthreads();
  #pragma unroll
  for (int d = 1; d < 256; d <<= 1){
    int t = (threadIdx.x >= d) ? sm[threadIdx.x - d] : 0;
    __syncthreads();
    sm[threadIdx.x] += t;
    __syncthreads();
  }
  gbc[threadIdx.x] = sm[threadIdx.x] - v2;
}

__global__ __launch_bounds__(256) void k_scan3(int* __restrict__ off, const int* __restrict__ bsum,
                                               int* __restrict__ cursor, int n, int etot){
  int i = blockIdx.x * 256 + threadIdx.x;
  if (i < n){
    int o = off[i] + bsum[blockIdx.x];
    off[i] = o;
    cursor[i] = o;
  }
  if (i == 0) off[n] = etot;
}

// ---------- bucketed scatter pass 1: (src,dst) pairs into dst>>8 buckets ----------
__global__ __launch_bounds__(256) void k_bucket1(const int* __restrict__ ei, int* __restrict__ gbc,
                                                 uint2* __restrict__ ebuck, int e, int etot){
  __shared__ int h[256], base[256], lc[256];
  const int tid = threadIdx.x;
  h[tid] = 0;
  __syncthreads();
  int i0 = blockIdx.x * 1024;
  int iend = min(i0 + 1024, etot);
  uint2 ed[4]; int ne = 0;
  for (int t = i0 + tid; t < iend; t += 256){
    int s_, d_;
    if (t < e){ s_ = ei[t]; d_ = ei[e + t]; } else { s_ = d_ = t - e; }
    ed[ne].x = (unsigned)s_; ed[ne].y = (unsigned)d_; ++ne;
    atomicAdd(&h[d_ >> 8], 1);
  }
  __syncthreads();
  base[tid] = h[tid] ? atomicAdd(&gbc[tid], h[tid]) : 0;
  lc[tid] = 0;
  __syncthreads();
  for (int q = 0; q < ne; ++q){
    int b = ed[q].y >> 8;
    int p = base[b] + atomicAdd(&lc[b], 1);
    ebuck[p] = ed[q];
  }
}

// ---------- bucketed scatter pass 2: fine scatter (locality-confined) ----------
__global__ __launch_bounds__(256) void k_bucket2(const uint2* __restrict__ ebuck, int* __restrict__ cursor,
                                                 int* __restrict__ csr, int etot){
  int t = blockIdx.x * 256 + threadIdx.x;
  if (t >= etot) return;
  uint2 p = ebuck[t];
  int pos = atomicAdd(&cursor[p.y], 1);
  csr[pos] = (int)p.x;
}

// ---------- fused GAT edge phase: one wave per dst node, unroll-8 gather MLP ----------
__global__ __launch_bounds__(256) void k_gatconv(const int* __restrict__ off, const int* __restrict__ csr,
                                                 const float* __restrict__ asrc, const float* __restrict__ adst,
                                                 const unsigned short* __restrict__ xpb,
                                                 const float* __restrict__ bias,
                                                 unsigned short* __restrict__ outb, int n){
  int w = (blockIdx.x * 256 + threadIdx.x) >> 6;
  int lane = threadIdx.x & 63;
  if (w >= n) return;
  const int o0 = off[w], o1 = off[w + 1];
  const float ad = adst[w];
  float m = -1e30f;
  for (int j = o0 + lane; j < o1; j += 64){
    float v = asrc[csr[j]] + ad;
    v = (v > 0.0f) ? v : 0.2f * v;
    m = fmaxf(m, v);
  }
  #pragma unroll
  for (int d = 32; d > 0; d >>= 1) m = fmaxf(m, __shfl_xor(m, d));
  float s = 0.0f, acc0 = 0.0f, acc1 = 0.0f;
  for (int base = o0; base < o1; base += 64){
    int j = base + lane;
    float wgt = 0.0f;
    int src = 0;
    if (j < o1){
      src = csr[j];
      float v = asrc[src] + ad;
      v = (v > 0.0f) ? v : 0.2f * v;
      wgt = __expf(v - m);
    }
    s += wgt;
    const int cnt8 = (min(64, o1 - base) + 7) & ~7;
    const int wbits = __float_as_int(wgt);
    for (int t = 0; t < cnt8; t += 8){
      unsigned uu[8]; float wq[8];
      #pragma unroll
      for (int q = 0; q < 8; ++q){
        int sr = __builtin_amdgcn_readlane(src, t + q);
        wq[q] = __int_as_float(__builtin_amdgcn_readlane(wbits, t + q));
        uu[q] = *(const unsigned*)&xpb[(size_t)sr * D + 2 * lane];
      }
      #pragma unroll
      for (int q = 0; q < 8; ++q){
        acc0 = fmaf(wq[q], __uint_as_float(uu[q] << 16), acc0);
        acc1 = fmaf(wq[q], __uint_as_float(uu[q] & 0xFFFF0000u), acc1);
      }
    }
  }
  #pragma unroll
  for (int d = 32; d > 0; d >>= 1) s += __shfl_xor(s, d);
  float inv = 1.0f / (s + 1e-16f);
  float2 bv = *(const float2*)&bias[2 * lane];
  unsigned pack = ((unsigned)f2bf(acc1 * inv + bv.y) << 16) | f2bf(acc0 * inv + bv.x);
  *(unsigned*)&outb[(size_t)w * D + 2 * lane] = pack;
}

// ---------- fused GRU dual-GEMM: BM=64, 8 waves, wave owns 16 H-cols, packed weights ----------
template<int RELU>
__global__ __launch_bounds__(512) void k_grugemm(const unsigned short* __restrict__ hgb,
                                                 const float* __restrict__ xprev,
                                                 const unsigned short* __restrict__ Pu, // packed frag order
                                                 const float* __restrict__ bih,
                                                 const float* __restrict__ bhh,
                                                 float* __restrict__ out, int n){
  __shared__ __align__(16) unsigned short A1lds[64 * 128];  // 16 KB (hg, bf16)
  __shared__ __align__(16) unsigned short A2lds[64 * 128];  // 16 KB (xprev->bf16)
  const int tid = threadIdx.x;
  const int lane = tid & 63;
  const int w = tid >> 6;               // 0..7
  const int row0 = blockIdx.x * 64;

  #pragma unroll
  for (int r = 0; r < 2; ++r){
    int u = r * 512 + tid;
    int row = u >> 4, c16 = u & 15;
    int gr = row0 + row;
    int c16s = slot16(c16, row);
    u32x4 v1 = {0,0,0,0};
    union { unsigned short s[8]; bf16x8 v; } t2;
    #pragma unroll
    for (int q = 0; q < 8; ++q) t2.s[q] = 0;
    if (gr < n){
      v1 = *(const u32x4*)(hgb + (size_t)gr * 128 + c16 * 8);
      const float* p = xprev + (size_t)gr * 128 + c16 * 8;
      float4 f0 = *(const float4*)p, f1 = *(const float4*)(p + 4);
      t2.s[0]=f2bf(f0.x); t2.s[1]=f2bf(f0.y); t2.s[2]=f2bf(f0.z); t2.s[3]=f2bf(f0.w);
      t2.s[4]=f2bf(f1.x); t2.s[5]=f2bf(f1.y); t2.s[6]=f2bf(f1.z); t2.s[7]=f2bf(f1.w);
    }
    *(u32x4*)&A1lds[row * 128 + c16s * 8] = v1;
    *(bf16x8*)&A2lds[row * 128 + c16s * 8] = t2.v;
  }
  __syncthreads();

  f32x4 accR[4], accZ[4], accN[4], accH[4];
  #pragma unroll
  for (int mf = 0; mf < 4; ++mf)
    #pragma unroll
    for (int i = 0; i < 4; ++i){ accR[mf][i]=0.f; accZ[mf][i]=0.f; accN[mf][i]=0.f; accH[mf][i]=0.f; }

  const int l15 = lane & 15, lg = lane >> 4;
  const int cw = w * 16 + l15;          // this lane's output column (0..127)
  #pragma unroll
  for (int kk = 0; kk < 4; ++kk){
    const int c16 = kk * 4 + lg;
    const unsigned short* Pb = Pu + (size_t)(w * 4 + kk) * 3072 + lane * 8;
    bf16x8 bir = *(const bf16x8*)&Pb[0];
    bf16x8 bhr = *(const bf16x8*)&Pb[512];
    bf16x8 biz = *(const bf16x8*)&Pb[1024];
    bf16x8 bhz = *(const bf16x8*)&Pb[1536];
    bf16x8 bin = *(const bf16x8*)&Pb[2048];
    bf16x8 bhn = *(const bf16x8*)&Pb[2560];
    bf16x8 a1[4], a2[4];
    #pragma unroll
    for (int mf = 0; mf < 4; ++mf){
      int row = mf * 16 + l15;
      int o = row * 128 + slot16(c16, row) * 8;
      a1[mf] = *(bf16x8*)&A1lds[o];
      a2[mf] = *(bf16x8*)&A2lds[o];
    }
    #pragma unroll
    for (int mf = 0; mf < 4; ++mf){
      accR[mf] = __builtin_amdgcn_mfma_f32_16x16x32_bf16(a1[mf], bir, accR[mf], 0, 0, 0);
      accR[mf] = __builtin_amdgcn_mfma_f32_16x16x32_bf16(a2[mf], bhr, accR[mf], 0, 0, 0);
      accZ[mf] = __builtin_amdgcn_mfma_f32_16x16x32_bf16(a1[mf], biz, accZ[mf], 0, 0, 0);
      accZ[mf] = __builtin_amdgcn_mfma_f32_16x16x32_bf16(a2[mf], bhz, accZ[mf], 0, 0, 0);
      accN[mf] = __builtin_amdgcn_mfma_f32_16x16x32_bf16(a1[mf], bin, accN[mf], 0, 0, 0);
      accH[mf] = __builtin_amdgcn_mfma_f32_16x16x32_bf16(a2[mf], bhn, accH[mf], 0, 0, 0);
    }
  }

  const float sbR = bih[cw] + bhh[cw];
  const float sbZ = bih[cw + 128] + bhh[cw + 128];
  const float biN = bih[cw + 256], bhN = bhh[cw + 256];
  #pragma unroll
  for (int mf = 0; mf < 4; ++mf)
    #pragma unroll
    for (int i = 0; i < 4; ++i){
      int rr = row0 + mf * 16 + lg * 4 + i;
      if (rr < n){
        float r  = fsigmoid(accR[mf][i] + sbR);
        float z  = fsigmoid(accZ[mf][i] + sbZ);
        float nn = ftanh(accN[mf][i] + biN + r * (accH[mf][i] + bhN));
        float hp = xprev[(size_t)rr * 128 + cw];
        float h = (1.0f - z) * nn + z * hp;
        if (RELU) h = fmaxf(h, 0.0f);
        out[(size_t)rr * 128 + cw] = h;
      }
    }
}

// ---------- BatchNorm normalize ----------
__global__ __launch_bounds__(256) void k_bnnorm(float* __restrict__ H, const float* __restrict__ bns, int n){
  int idx = blockIdx.x * 256 + threadIdx.x;
  if (idx >= n * D) return;
  int c = idx & 127;
  float inv_n = 1.0f / (float)n;
  float mu = bns[c] * inv_n;
  float var = bns[D + c] * inv_n - mu * mu;
  H[idx] = (H[idx] - mu) / sqrtf(var + 1e-5f);
}

// ---------- launch ----------
extern "C" void kernel_launch(void* const* d_in, const int* in_sizes, int n_in,
                              void* d_out, int out_size, void* d_ws, size_t ws_size,
                              hipStream_t stream){
  const float* nf     = (const float*)d_in[0];
  const int*   ei     = (const int*)  d_in[1];
  const float* xprev[2] = { (const float*)d_in[2], (const float*)d_in[3] };
  const float* ts     = (const float*)d_in[4];
  const float* freq   = (const float*)d_in[5];
  const float* phase  = (const float*)d_in[6];
  const float* mergeW = (const float*)d_in[7];
  const float* mergeb = (const float*)d_in[8];
  const float* gatW[2]  = { (const float*)d_in[9],  (const float*)d_in[17] };
  const float* gatAS[2] = { (const float*)d_in[10], (const float*)d_in[18] };
  const float* gatAD[2] = { (const float*)d_in[11], (const float*)d_in[19] };
  const float* gatB[2]  = { (const float*)d_in[12], (const float*)d_in[20] };
  const float* Wih[2]   = { (const float*)d_in[13], (const float*)d_in[21] };
  const float* Whh[2]   = { (const float*)d_in[14], (const float*)d_in[22] };
  const float* bih[2]   = { (const float*)d_in[15], (const float*)d_in[23] };
  const float* bhh[2]   = { (const float*)d_in[16], (const float*)d_in[24] };
  const float* skipW  = (const float*)d_in[25];
  const float* skipb  = (const float*)d_in[26];

  const int n = in_sizes[0] / D;      // 50000
  const int e = in_sizes[1] / 2;      // 640000
  const int etot = e + n;             // 690000
  const size_t nd = (size_t)n * D;

  // workspace carve (4-byte words)
  float* ws   = (float*)d_ws;
  float* asrc = ws;                        // n
  float* adst = asrc + n;                  // n
  float* bns  = adst + n;                  // 2*D
  int*   off  = (int*)(bns + 2 * D);       // n+1
  int*   cnt  = off + n + 1;               // n
  int*   bsum = cnt + n;                   // 256
  int*   gbh  = bsum + 256;                // 256
  int*   gbc  = gbh + 256;                 // 256
  int*   csr  = gbc + 256;                 // etot
  uintptr_t ba = ((uintptr_t)(csr + etot) + 7) & ~(uintptr_t)7;
  uint2* ebuck = (uint2*)ba;               // etot pairs (8B each)
  uintptr_t pa = ((uintptr_t)(ebuck + etot) + 15) & ~(uintptr_t)15;
  unsigned short* Pm  = (unsigned short*)pa;   // 32768 (merge packed)
  unsigned short* Pg0 = Pm  + 32768;           // 16384 each
  unsigned short* Pg1 = Pg0 + 16384;
  unsigned short* Psk = Pg1 + 16384;
  unsigned short* Pu0 = Psk + 16384;           // 98304 each (gru packed)
  unsigned short* Pu1 = Pu0 + 98304;
  unsigned short* xb  = Pu1 + 98304;           // n*128 bf16
  unsigned short* xpb = xb  + nd;              // n*128 bf16
  unsigned short* hgb = xpb + nd;              // n*128 bf16

  float* H1 = (float*)d_out;
  float* H2 = H1 + nd;

  const dim3 b256(256);
  const int nb_nd = (int)((nd + 255) / 256);
  const int nb_e  = (etot + 255) / 256;
  const int nb_n  = (n + 255) / 256;
  const int grows = (n + 63) / 64;         // 782
  const dim3 gm1(1, grows);
  const int gru_blocks = (n + 63) / 64;
  const int nb_wave = (int)(((size_t)n * 64 + 255) / 256);

  // ---- CSR build (bucketed scatter for write locality) ----
  k_init0<<<nb_n, b256, 0, stream>>>(cnt, bns, gbh, n);
  k_hist<<<(etot + 4095) / 4096, b256, 0, stream>>>(ei, cnt, gbh, e, etot);
  k_scan1<<<nb_n, b256, 0, stream>>>(cnt, off, bsum, n);
  k_scan2<<<1, b256, 0, stream>>>(bsum, nb_n, gbh, gbc);
  k_scan3<<<nb_n, b256, 0, stream>>>(off, bsum, cnt, n, etot);
  k_bucket1<<<(etot + 1023) / 1024, b256, 0, stream>>>(ei, gbc, ebuck, e, etot);
  k_bucket2<<<nb_e, b256, 0, stream>>>(ebuck, cnt, csr, etot);

  // ---- pack all weights (bf16, fragment order) ----
  k_wpackall<<<(278528 + 255) / 256, b256, 0, stream>>>(
      mergeW, gatW[0], gatW[1], skipW, Wih[0], Whh[0], Wih[1], Whh[1],
      Pm, Pg0, Pg1, Psk, Pu0, Pu1);

  // ---- merge: xb = bf16([nf, cos] @ mergeW + mergeb) ----
  k_merge<<<gm1, b256, 0, stream>>>(nf, ts, freq, phase, Pm, mergeb, xb, n);

  for (int L = 0; L < 2; ++L){
    float* gout = (L == 0) ? H1 : H2;
    const unsigned short* wtg = (L == 0) ? Pg0 : Pg1;
    const unsigned short* pu  = (L == 0) ? Pu0 : Pu1;
    if (L == 0)
      k_mgemm<true , true, false, false, true, false><<<gm1, b256, 0, stream>>>(
          xb, wtg, nullptr, xpb, n, gatAS[0], gatAD[0], asrc, adst, nullptr);
    else
      k_mgemm<false, true, false, false, true, false><<<gm1, b256, 0, stream>>>(
          H1, wtg, nullptr, xpb, n, gatAS[1], gatAD[1], asrc, adst, nullptr);
    k_gatconv<<<nb_wave, b256, 0, stream>>>(off, csr, asrc, adst, xpb, gatB[L], hgb, n);
    if (L == 0)
      k_grugemm<1><<<gru_blocks, dim3(512), 0, stream>>>(hgb, xprev[0], pu, bih[0], bhh[0], gout, n);
    else
      k_grugemm<0><<<gru_blocks, dim3(512), 0, stream>>>(hgb, xprev[1], pu, bih[1], bhh[1], gout, n);
  }

  // skip: H2 += xb @ skipW + skipb, fused BN column reduce
  k_mgemm<true, false, true, true, false, true><<<gm1, b256, 0, stream>>>(
      xb, Psk, skipb, H2, n, nullptr, nullptr, nullptr, nullptr, bns);
  // BatchNorm normalize
  k_bnnorm<<<nb_nd, b256, 0, stream>>>(H2, bns, n);
}